// Round 15
// baseline (335.158 us; speedup 1.0000x reference)
//
#include <hip/hip_runtime.h>
#include <hip/hip_bf16.h>

#define NNODES 50000
#define NEDGES 500000
#define INCH 128
#define HID 64
#define HEADS 4
#define FDIM 256
#define NGRAPHS 64
#define OUTCH 16
#define NEG_SLOPE 0.2f
#define LOG2E 1.44269504089f

#define BM 64
#define BN 256
#define BK 32

typedef float f32x4 __attribute__((ext_vector_type(4)));
typedef _Float16 f16x8 __attribute__((ext_vector_type(8)));
typedef _Float16 f16x4 __attribute__((ext_vector_type(4)));
typedef __fp16 h16x2 __attribute__((ext_vector_type(2)));   // builtin-compatible v2f16

__device__ inline void gld_lds16(const void* g, void* l) {
    __builtin_amdgcn_global_load_lds((__attribute__((address_space(1))) void*)g,
                                     (__attribute__((address_space(3))) void*)l, 16, 0, 0);
}

// ---------------- CSR build ----------------

__global__ void k_hist(const int* __restrict__ dst, int E, int* __restrict__ counts) {
    int i = blockIdx.x * blockDim.x + threadIdx.x;
    if (i < E) atomicAdd(&counts[dst[i]], 1);
}

__global__ __launch_bounds__(256) void k_blocksum(const int* __restrict__ counts, int N,
                                                  int* __restrict__ bsum) {
    int idx = blockIdx.x * 256 + threadIdx.x;
    int v = (idx < N) ? counts[idx] : 0;
#pragma unroll
    for (int off = 32; off; off >>= 1) v += __shfl_xor(v, off);
    __shared__ int wsum[4];
    if ((threadIdx.x & 63) == 0) wsum[threadIdx.x >> 6] = v;
    __syncthreads();
    if (threadIdx.x == 0) bsum[blockIdx.x] = wsum[0] + wsum[1] + wsum[2] + wsum[3];
}

__global__ __launch_bounds__(256) void k_scanfinal(const int* __restrict__ counts,
                                                   const int* __restrict__ bsum, int N,
                                                   int* __restrict__ rowstart,
                                                   int* __restrict__ cursor) {
    __shared__ int tmp[256];
    __shared__ int wsum[4];
    int t = threadIdx.x, b = blockIdx.x;
    int p = 0;
    for (int i = t; i < b; i += 256) p += bsum[i];
#pragma unroll
    for (int off = 32; off; off >>= 1) p += __shfl_xor(p, off);
    int idx = b * 256 + t;
    int v = (idx < N) ? counts[idx] : 0;
    tmp[t] = v;
    if ((t & 63) == 0) wsum[t >> 6] = p;
    __syncthreads();
    int bp = wsum[0] + wsum[1] + wsum[2] + wsum[3];
    for (int off = 1; off < 256; off <<= 1) {
        int u = (t >= off) ? tmp[t - off] : 0;
        __syncthreads();
        tmp[t] += u;
        __syncthreads();
    }
    if (idx < N) {
        int incl = bp + tmp[t];
        rowstart[idx + 1] = incl;
        cursor[idx] = incl - v;
    }
    if (idx == 0) rowstart[0] = 0;
}

__global__ void k_scatter(const int* __restrict__ src, const int* __restrict__ dst, int E,
                          int* __restrict__ cursor, int* __restrict__ csr_src) {
    int i = blockIdx.x * blockDim.x + threadIdx.x;
    if (i < E) {
        int p = atomicAdd(&cursor[dst[i]], 1);
        csr_src[p] = src[i];
    }
}

// ---------------- fused conversion: x -> f16 plane, W[l] -> transposed f16 ----------------

__device__ inline void wdecomp_body(const float* __restrict__ W, _Float16* __restrict__ Wt,
                                    int K, int bb) {
    int i = bb * 256 + threadIdx.x;
    int k = i >> 8, n = i & 255;
    Wt[n * K + k] = (_Float16)W[i];
}

__global__ __launch_bounds__(256) void k_convert(
    const float* __restrict__ X, _Float16* __restrict__ Xf, int bx,
    const float* __restrict__ W0, _Float16* __restrict__ Wt0,
    const float* __restrict__ W1, _Float16* __restrict__ Wt1,
    const float* __restrict__ W2, _Float16* __restrict__ Wt2) {
    int b = blockIdx.x;
    if (b < bx) {
        int i = b * 256 + threadIdx.x;
        float4 v = ((const float4*)X)[i];
        f16x4 o = {(_Float16)v.x, (_Float16)v.y, (_Float16)v.z, (_Float16)v.w};
        ((f16x4*)Xf)[i] = o;
    } else if (b < bx + 128) {
        wdecomp_body(W0, Wt0, INCH, b - bx);
    } else if (b < bx + 384) {
        wdecomp_body(W1, Wt1, FDIM, b - bx - 128);
    } else {
        wdecomp_body(W2, Wt2, FDIM, b - bx - 384);
    }
}

// ---------------- f16 MFMA GEMM, BM=64, double-buffered gld_lds, fused scores ----------------
// (measured-good version, unchanged: scores pre-scaled by LOG2E)

__global__ __launch_bounds__(256) void k_gemm_mfma(
    const _Float16* __restrict__ A, const _Float16* __restrict__ B,
    const float* __restrict__ av, const float* __restrict__ dv,
    _Float16* __restrict__ Hf,
    float* __restrict__ ssrcO, float* __restrict__ sdstO, int M, int K) {
    __shared__ _Float16 sA[2][BM * BK];
    __shared__ _Float16 sB[2][BN * BK];

    const int t = threadIdx.x;
    const int row0 = blockIdx.x * BM;
    const int wv = t >> 6, ln = t & 63, lr = ln & 15, lk = ln >> 4;

    const int ar = wv * 16 + (ln >> 2);
    const int alc = (ln & 3) ^ ((ar >> 1) & 3);
    const size_t agoff = (size_t)min(row0 + ar, M - 1) * K + alc * 8;
    const int fsc = lk ^ ((lr >> 1) & 3);

    f32x4 acc[4][4] = {};
    const int nt = K / BK;

#define STAGE(tt, p)                                                        \
    do {                                                                    \
        int _k0 = (tt)*BK;                                                  \
        gld_lds16(A + agoff + _k0, &sA[p][wv * 512]);                       \
        _Pragma("unroll") for (int _j = 0; _j < 4; ++_j) {                  \
            int _br = _j * 64 + ar;                                         \
            gld_lds16(B + (size_t)_br * K + _k0 + alc * 8,                  \
                      &sB[p][_j * 2048 + wv * 512]);                        \
        }                                                                   \
    } while (0)

    STAGE(0, 0);
    __syncthreads();
    for (int tt = 0; tt < nt; ++tt) {
        int cur = tt & 1;
        if (tt + 1 < nt) STAGE(tt + 1, cur ^ 1);

        f16x8 af[4];
#pragma unroll
        for (int mi = 0; mi < 4; ++mi)
            af[mi] = *(const f16x8*)&sA[cur][(mi * 16 + lr) * BK + fsc * 8];
#pragma unroll
        for (int ni = 0; ni < 4; ++ni) {
            f16x8 bf = *(const f16x8*)&sB[cur][(wv * 64 + ni * 16 + lr) * BK + fsc * 8];
#pragma unroll
            for (int mi = 0; mi < 4; ++mi)
                acc[mi][ni] = __builtin_amdgcn_mfma_f32_16x16x32_f16(af[mi], bf, acc[mi][ni], 0, 0, 0);
        }
        __syncthreads();
    }
#undef STAGE

    float ps[4][4] = {}, pd[4][4] = {};
#pragma unroll
    for (int ni = 0; ni < 4; ++ni) {
        int col = wv * 64 + ni * 16 + lr;
        float a_s = av[col] * LOG2E, a_d = dv[col] * LOG2E;
#pragma unroll
        for (int mi = 0; mi < 4; ++mi) {
            f32x4 v = acc[mi][ni];
            int r = row0 + mi * 16 + lk * 4;
#pragma unroll
            for (int j = 0; j < 4; ++j) {
                if (r + j < M) Hf[(size_t)(r + j) * FDIM + col] = (_Float16)v[j];
                ps[mi][j] += v[j] * a_s;
                pd[mi][j] += v[j] * a_d;
            }
        }
    }
#pragma unroll
    for (int mi = 0; mi < 4; ++mi) {
#pragma unroll
        for (int j = 0; j < 4; ++j) {
            float s = ps[mi][j], q = pd[mi][j];
            s += __shfl_xor(s, 1); s += __shfl_xor(s, 2);
            s += __shfl_xor(s, 4); s += __shfl_xor(s, 8);
            q += __shfl_xor(q, 1); q += __shfl_xor(q, 2);
            q += __shfl_xor(q, 4); q += __shfl_xor(q, 8);
            if (lr == 0) {
                int r = row0 + mi * 16 + lk * 4 + j;
                if (r < M) {
                    ssrcO[r * HEADS + wv] = s;
                    sdstO[r * HEADS + wv] = q;
                }
            }
        }
    }
}

// ---------------- flash softmax + aggregation: split-wave + v_dot2_f32_f16 inner ----------------
// Lanes 0-31: even edges (+self); lanes 32-63: odd edges. 8 features/lane (16B gathers).
// Edge weights packed to half2 (cvt_pkrtz) and applied via fdot2 (f16xf16 -> f32 acc).

__global__ __launch_bounds__(256) void k_aggregate(
    const _Float16* __restrict__ hf,
    const float* __restrict__ ssrc, const float* __restrict__ sdst,
    const int* __restrict__ rowstart, const int* __restrict__ csr_src,
    const float* __restrict__ bias,
    _Float16* __restrict__ outf, int N) {
    int wv = threadIdx.x >> 6, ln = threadIdx.x & 63;
    int n = blockIdx.x * 4 + wv;
    if (n >= N) return;
    int half = ln >> 5;
    int lh = ln & 31;
    int head = lh >> 3;
    int fo = lh * 8;
    float sd = sdst[n * HEADS + head];

    float m, d;
    float acc[8];
    {
        f16x8 sv = *(const f16x8*)&hf[(size_t)n * FDIM + fo];
        float e = ssrc[n * HEADS + head] + sd;
        e = (e > 0.f) ? e : NEG_SLOPE * e;
        if (half == 0) {
            m = e; d = 1.0f;
#pragma unroll
            for (int j = 0; j < 8; ++j) acc[j] = (float)sv[j];
        } else {
            m = -1e30f; d = 0.0f;
#pragma unroll
            for (int j = 0; j < 8; ++j) acc[j] = 0.f;
        }
    }
    int r0 = rowstart[n], r1 = rowstart[n + 1];
    int cnt = r1 - r0;
    for (int base = 0; base < cnt; base += 8) {
        int s[4];
        f16x8 u[4];
        float c[4], w[4];
#pragma unroll
        for (int i = 0; i < 4; ++i)
            s[i] = csr_src[min(r0 + base + 2 * i + half, r1 - 1)];
#pragma unroll
        for (int i = 0; i < 4; ++i) u[i] = *(const f16x8*)&hf[(size_t)s[i] * FDIM + fo];
#pragma unroll
        for (int i = 0; i < 4; ++i) {
            float sc = ssrc[s[i] * HEADS + head] + sd;
            sc = (sc > 0.f) ? sc : NEG_SLOPE * sc;
            c[i] = (base + 2 * i + half < cnt) ? sc : -1e30f;
        }
        float mx = fmaxf(fmaxf(c[0], c[1]), fmaxf(c[2], c[3]));
        float mn = fmaxf(m, mx);
        float wa = __builtin_amdgcn_exp2f(m - mn);
#pragma unroll
        for (int i = 0; i < 4; ++i) w[i] = __builtin_amdgcn_exp2f(c[i] - mn);
        h16x2 h01 = __builtin_amdgcn_cvt_pkrtz(w[0], w[1]);
        h16x2 h23 = __builtin_amdgcn_cvt_pkrtz(w[2], w[3]);
#pragma unroll
        for (int j = 0; j < 8; ++j) {
            h16x2 p01 = {(__fp16)u[0][j], (__fp16)u[1][j]};
            h16x2 p23 = {(__fp16)u[2][j], (__fp16)u[3][j]};
            float tj = acc[j] * wa;
            tj = __builtin_amdgcn_fdot2(h01, p01, tj, false);
            tj = __builtin_amdgcn_fdot2(h23, p23, tj, false);
            acc[j] = tj;
        }
        // keep d consistent with the f16-rounded weights used in acc
        float w01 = (float)h01[0] + (float)h01[1];
        float w23 = (float)h23[0] + (float)h23[1];
        d = d * wa + (w01 + w23);
        m = mn;
    }
    // ---- merge the two half-wave flash states ----
    {
        float pm = __shfl_xor(m, 32);
        float mn = fmaxf(m, pm);
        float wa = __builtin_amdgcn_exp2f(m - mn);
        float wb = __builtin_amdgcn_exp2f(pm - mn);
        float pd = __shfl_xor(d, 32);
        d = d * wa + pd * wb;
#pragma unroll
        for (int j = 0; j < 8; ++j) {
            float pa = __shfl_xor(acc[j], 32);
            acc[j] = acc[j] * wa + pa * wb;
        }
    }
    if (half == 0) {
        float inv = 1.0f / d;
        float4 b0 = *(const float4*)&bias[fo];
        float4 b1 = *(const float4*)&bias[fo + 4];
        f16x8 o;
        o[0] = (_Float16)fmaxf(acc[0] * inv + b0.x, 0.f);
        o[1] = (_Float16)fmaxf(acc[1] * inv + b0.y, 0.f);
        o[2] = (_Float16)fmaxf(acc[2] * inv + b0.z, 0.f);
        o[3] = (_Float16)fmaxf(acc[3] * inv + b0.w, 0.f);
        o[4] = (_Float16)fmaxf(acc[4] * inv + b1.x, 0.f);
        o[5] = (_Float16)fmaxf(acc[5] * inv + b1.y, 0.f);
        o[6] = (_Float16)fmaxf(acc[6] * inv + b1.z, 0.f);
        o[7] = (_Float16)fmaxf(acc[7] * inv + b1.w, 0.f);
        *(f16x8*)&outf[(size_t)n * FDIM + fo] = o;
    }
}

// ---------------- pooling (batch sorted, f16 plane) ----------------

__global__ __launch_bounds__(256) void k_pool(const _Float16* __restrict__ hf,
                                              const int* __restrict__ batch,
                                              float* __restrict__ pooled, int N) {
    int f = threadIdx.x;
    int n0 = blockIdx.x * 128;
    if (n0 >= N) return;
    int n1 = min(n0 + 128, N);
    int g = batch[n0];
    float run = 0.f;
    for (int n = n0; n < n1; ++n) {
        int gn = batch[n];
        if (gn != g) {
            atomicAdd(&pooled[g * FDIM + f], run);
            run = 0.f;
            g = gn;
        }
        run += (float)hf[(size_t)n * FDIM + f];
    }
    atomicAdd(&pooled[g * FDIM + f], run);
}

// ---------------- final classifier ----------------

__global__ __launch_bounds__(256) void k_final(const float* __restrict__ pooled,
                                               const float* __restrict__ Wc,
                                               const float* __restrict__ bc,
                                               float* __restrict__ out) {
    int tid = blockIdx.x * 256 + threadIdx.x;
    int g = tid >> 4, o = tid & 15;
    float s = bc[o];
    for (int k = 0; k < FDIM; ++k) s += pooled[g * FDIM + k] * Wc[k * OUTCH + o];
    out[g * OUTCH + o] = s;
}

// ---------------- launch ----------------

extern "C" void kernel_launch(void* const* d_in, const int* in_sizes, int n_in,
                              void* d_out, int out_size, void* d_ws, size_t ws_size,
                              hipStream_t stream) {
    const float* x = (const float*)d_in[0];
    const int* edge_index = (const int*)d_in[2];
    const int* batch = (const int*)d_in[3];
    const float* W[3]    = {(const float*)d_in[4], (const float*)d_in[8],  (const float*)d_in[12]};
    const float* asrc[3] = {(const float*)d_in[5], (const float*)d_in[9],  (const float*)d_in[13]};
    const float* adst[3] = {(const float*)d_in[6], (const float*)d_in[10], (const float*)d_in[14]};
    const float* bias[3] = {(const float*)d_in[7], (const float*)d_in[11], (const float*)d_in[15]};
    const float* Wc = (const float*)d_in[16];
    const float* bc = (const float*)d_in[17];

    const int N = in_sizes[3];
    const int E = in_sizes[2] / 2;
    const int* e_src = edge_index;
    const int* e_dst = edge_index + E;

    char* ws = (char*)d_ws;
    size_t off = 0;
    _Float16* hb = (_Float16*)(ws + off); off += (size_t)N * FDIM * 2;
    _Float16* xf = (_Float16*)(ws + off); off += (size_t)N * INCH * 2;
    _Float16* P  = (_Float16*)(ws + off); off += (size_t)N * FDIM * 2;
    float* ssrc = (float*)(ws + off); off += (size_t)N * HEADS * 4;
    float* sdst = (float*)(ws + off); off += (size_t)N * HEADS * 4;
    int* rowstart = (int*)(ws + off); off += ((size_t)(N + 1) * 4 + 255) / 256 * 256;
    int* counts = (int*)(ws + off); off += (size_t)N * 4;
    int* cursor = (int*)(ws + off); off += (size_t)N * 4;
    int* csr_src = (int*)(ws + off); off += (size_t)E * 4;
    float* pooled = (float*)(ws + off); off += (size_t)NGRAPHS * FDIM * 4;
    int* bsum = (int*)(ws + off); off += ((size_t)((N + 255) / 256) * 4 + 255) / 256 * 256;
    _Float16* Wt[3];
    int Ks[3] = {INCH, FDIM, FDIM};
    for (int l = 0; l < 3; ++l) {
        Wt[l] = (_Float16*)(ws + off); off += (size_t)256 * Ks[l] * 2;
    }

    const int nb = (N + 255) / 256;

    // ---- CSR build ----
    hipMemsetAsync(counts, 0, (size_t)N * 4, stream);
    k_hist<<<(E + 255) / 256, 256, 0, stream>>>(e_dst, E, counts);
    k_blocksum<<<nb, 256, 0, stream>>>(counts, N, bsum);
    k_scanfinal<<<nb, 256, 0, stream>>>(counts, bsum, N, rowstart, cursor);
    k_scatter<<<(E + 255) / 256, 256, 0, stream>>>(e_src, e_dst, E, cursor, csr_src);

    // ---- fused input + weight conversion (1 launch) ----
    {
        int bx = (N * INCH / 4) / 256;
        int btot = bx + (Ks[0] * 256) / 256 + (Ks[1] * 256) / 256 + (Ks[2] * 256) / 256;
        k_convert<<<btot, 256, 0, stream>>>(x, xf, bx, W[0], Wt[0], W[1], Wt[1], W[2], Wt[2]);
    }

    // ---- 3 GAT layers ----
    const _Float16* Af = xf;
    for (int l = 0; l < 3; ++l) {
        int K = Ks[l];
        k_gemm_mfma<<<(N + BM - 1) / BM, 256, 0, stream>>>(Af, Wt[l], asrc[l], adst[l],
                                                           hb, ssrc, sdst, N, K);
        k_aggregate<<<(N + 3) / 4, 256, 0, stream>>>(hb, ssrc, sdst, rowstart, csr_src,
                                                     bias[l], P, N);
        Af = P;
    }

    // ---- pool + classifier ----
    hipMemsetAsync(pooled, 0, (size_t)NGRAPHS * FDIM * 4, stream);
    k_pool<<<(N + 127) / 128, 256, 0, stream>>>(P, batch, pooled, N);
    k_final<<<4, 256, 0, stream>>>(pooled, Wc, bc, (float*)d_out);
}

// Round 16
// 331.870 us; speedup vs baseline: 1.0099x; 1.0099x over previous
//
#include <hip/hip_runtime.h>
#include <hip/hip_bf16.h>

#define NNODES 50000
#define NEDGES 500000
#define INCH 128
#define HID 64
#define HEADS 4
#define FDIM 256
#define NGRAPHS 64
#define OUTCH 16
#define NEG_SLOPE 0.2f
#define LOG2E 1.44269504089f

#define BM 64
#define BN 256
#define BK 32

typedef float f32x4 __attribute__((ext_vector_type(4)));
typedef _Float16 f16x8 __attribute__((ext_vector_type(8)));
typedef _Float16 f16x4 __attribute__((ext_vector_type(4)));
typedef __fp16 h16x2 __attribute__((ext_vector_type(2)));   // builtin-compatible v2f16

__device__ inline void gld_lds16(const void* g, void* l) {
    __builtin_amdgcn_global_load_lds((__attribute__((address_space(1))) void*)g,
                                     (__attribute__((address_space(3))) void*)l, 16, 0, 0);
}

// ---------------- CSR build ----------------

__global__ void k_hist(const int* __restrict__ dst, int E, int* __restrict__ counts) {
    int i = blockIdx.x * blockDim.x + threadIdx.x;
    if (i < E) atomicAdd(&counts[dst[i]], 1);
}

__global__ __launch_bounds__(256) void k_blocksum(const int* __restrict__ counts, int N,
                                                  int* __restrict__ bsum) {
    int idx = blockIdx.x * 256 + threadIdx.x;
    int v = (idx < N) ? counts[idx] : 0;
#pragma unroll
    for (int off = 32; off; off >>= 1) v += __shfl_xor(v, off);
    __shared__ int wsum[4];
    if ((threadIdx.x & 63) == 0) wsum[threadIdx.x >> 6] = v;
    __syncthreads();
    if (threadIdx.x == 0) bsum[blockIdx.x] = wsum[0] + wsum[1] + wsum[2] + wsum[3];
}

__global__ __launch_bounds__(256) void k_scanfinal(const int* __restrict__ counts,
                                                   const int* __restrict__ bsum, int N,
                                                   int* __restrict__ rowstart,
                                                   int* __restrict__ cursor) {
    __shared__ int tmp[256];
    __shared__ int wsum[4];
    int t = threadIdx.x, b = blockIdx.x;
    int p = 0;
    for (int i = t; i < b; i += 256) p += bsum[i];
#pragma unroll
    for (int off = 32; off; off >>= 1) p += __shfl_xor(p, off);
    int idx = b * 256 + t;
    int v = (idx < N) ? counts[idx] : 0;
    tmp[t] = v;
    if ((t & 63) == 0) wsum[t >> 6] = p;
    __syncthreads();
    int bp = wsum[0] + wsum[1] + wsum[2] + wsum[3];
    for (int off = 1; off < 256; off <<= 1) {
        int u = (t >= off) ? tmp[t - off] : 0;
        __syncthreads();
        tmp[t] += u;
        __syncthreads();
    }
    if (idx < N) {
        int incl = bp + tmp[t];
        rowstart[idx + 1] = incl;
        cursor[idx] = incl - v;
    }
    if (idx == 0) rowstart[0] = 0;
}

__global__ void k_scatter(const int* __restrict__ src, const int* __restrict__ dst, int E,
                          int* __restrict__ cursor, int* __restrict__ csr_src) {
    int i = blockIdx.x * blockDim.x + threadIdx.x;
    if (i < E) {
        int p = atomicAdd(&cursor[dst[i]], 1);
        csr_src[p] = src[i];
    }
}

// ---------------- fused conversion: x -> f16 plane, W[l] -> transposed f16 ----------------

__device__ inline void wdecomp_body(const float* __restrict__ W, _Float16* __restrict__ Wt,
                                    int K, int bb) {
    int i = bb * 256 + threadIdx.x;
    int k = i >> 8, n = i & 255;
    Wt[n * K + k] = (_Float16)W[i];
}

__global__ __launch_bounds__(256) void k_convert(
    const float* __restrict__ X, _Float16* __restrict__ Xf, int bx,
    const float* __restrict__ W0, _Float16* __restrict__ Wt0,
    const float* __restrict__ W1, _Float16* __restrict__ Wt1,
    const float* __restrict__ W2, _Float16* __restrict__ Wt2) {
    int b = blockIdx.x;
    if (b < bx) {
        int i = b * 256 + threadIdx.x;
        float4 v = ((const float4*)X)[i];
        f16x4 o = {(_Float16)v.x, (_Float16)v.y, (_Float16)v.z, (_Float16)v.w};
        ((f16x4*)Xf)[i] = o;
    } else if (b < bx + 128) {
        wdecomp_body(W0, Wt0, INCH, b - bx);
    } else if (b < bx + 384) {
        wdecomp_body(W1, Wt1, FDIM, b - bx - 128);
    } else {
        wdecomp_body(W2, Wt2, FDIM, b - bx - 384);
    }
}

// ---------------- f16 MFMA GEMM, BM=64, double-buffered gld_lds, fused scores ----------------
// (measured-good version, unchanged: scores pre-scaled by LOG2E)

__global__ __launch_bounds__(256) void k_gemm_mfma(
    const _Float16* __restrict__ A, const _Float16* __restrict__ B,
    const float* __restrict__ av, const float* __restrict__ dv,
    _Float16* __restrict__ Hf,
    float* __restrict__ ssrcO, float* __restrict__ sdstO, int M, int K) {
    __shared__ _Float16 sA[2][BM * BK];
    __shared__ _Float16 sB[2][BN * BK];

    const int t = threadIdx.x;
    const int row0 = blockIdx.x * BM;
    const int wv = t >> 6, ln = t & 63, lr = ln & 15, lk = ln >> 4;

    const int ar = wv * 16 + (ln >> 2);
    const int alc = (ln & 3) ^ ((ar >> 1) & 3);
    const size_t agoff = (size_t)min(row0 + ar, M - 1) * K + alc * 8;
    const int fsc = lk ^ ((lr >> 1) & 3);

    f32x4 acc[4][4] = {};
    const int nt = K / BK;

#define STAGE(tt, p)                                                        \
    do {                                                                    \
        int _k0 = (tt)*BK;                                                  \
        gld_lds16(A + agoff + _k0, &sA[p][wv * 512]);                       \
        _Pragma("unroll") for (int _j = 0; _j < 4; ++_j) {                  \
            int _br = _j * 64 + ar;                                         \
            gld_lds16(B + (size_t)_br * K + _k0 + alc * 8,                  \
                      &sB[p][_j * 2048 + wv * 512]);                        \
        }                                                                   \
    } while (0)

    STAGE(0, 0);
    __syncthreads();
    for (int tt = 0; tt < nt; ++tt) {
        int cur = tt & 1;
        if (tt + 1 < nt) STAGE(tt + 1, cur ^ 1);

        f16x8 af[4];
#pragma unroll
        for (int mi = 0; mi < 4; ++mi)
            af[mi] = *(const f16x8*)&sA[cur][(mi * 16 + lr) * BK + fsc * 8];
#pragma unroll
        for (int ni = 0; ni < 4; ++ni) {
            f16x8 bf = *(const f16x8*)&sB[cur][(wv * 64 + ni * 16 + lr) * BK + fsc * 8];
#pragma unroll
            for (int mi = 0; mi < 4; ++mi)
                acc[mi][ni] = __builtin_amdgcn_mfma_f32_16x16x32_f16(af[mi], bf, acc[mi][ni], 0, 0, 0);
        }
        __syncthreads();
    }
#undef STAGE

    float ps[4][4] = {}, pd[4][4] = {};
#pragma unroll
    for (int ni = 0; ni < 4; ++ni) {
        int col = wv * 64 + ni * 16 + lr;
        float a_s = av[col] * LOG2E, a_d = dv[col] * LOG2E;
#pragma unroll
        for (int mi = 0; mi < 4; ++mi) {
            f32x4 v = acc[mi][ni];
            int r = row0 + mi * 16 + lk * 4;
#pragma unroll
            for (int j = 0; j < 4; ++j) {
                if (r + j < M) Hf[(size_t)(r + j) * FDIM + col] = (_Float16)v[j];
                ps[mi][j] += v[j] * a_s;
                pd[mi][j] += v[j] * a_d;
            }
        }
    }
#pragma unroll
    for (int mi = 0; mi < 4; ++mi) {
#pragma unroll
        for (int j = 0; j < 4; ++j) {
            float s = ps[mi][j], q = pd[mi][j];
            s += __shfl_xor(s, 1); s += __shfl_xor(s, 2);
            s += __shfl_xor(s, 4); s += __shfl_xor(s, 8);
            q += __shfl_xor(q, 1); q += __shfl_xor(q, 2);
            q += __shfl_xor(q, 4); q += __shfl_xor(q, 8);
            if (lr == 0) {
                int r = row0 + mi * 16 + lk * 4 + j;
                if (r < M) {
                    ssrcO[r * HEADS + wv] = s;
                    sdstO[r * HEADS + wv] = q;
                }
            }
        }
    }
}

// ---------------- flash softmax + aggregation: split-wave + fdot2 + 2-stage pipeline ----------------
// Lanes 0-31: even edges (+self); lanes 32-63: odd edges. 8 features/lane (16B gathers).
// Iteration g issues group g+1's index/score/h loads before computing group g, so the
// ~500-cycle gather latency hides under compute (counted-vmcnt keeps them in flight).

__global__ __launch_bounds__(256) void k_aggregate(
    const _Float16* __restrict__ hf,
    const float* __restrict__ ssrc, const float* __restrict__ sdst,
    const int* __restrict__ rowstart, const int* __restrict__ csr_src,
    const float* __restrict__ bias,
    _Float16* __restrict__ outf, int N) {
    int wv = threadIdx.x >> 6, ln = threadIdx.x & 63;
    int n = blockIdx.x * 4 + wv;
    if (n >= N) return;
    int half = ln >> 5;
    int lh = ln & 31;
    int head = lh >> 3;
    int fo = lh * 8;
    float sd = sdst[n * HEADS + head];

    float m, d;
    float acc[8];
    {
        f16x8 sv = *(const f16x8*)&hf[(size_t)n * FDIM + fo];
        float e = ssrc[n * HEADS + head] + sd;
        e = (e > 0.f) ? e : NEG_SLOPE * e;
        if (half == 0) {
            m = e; d = 1.0f;
#pragma unroll
            for (int j = 0; j < 8; ++j) acc[j] = (float)sv[j];
        } else {
            m = -1e30f; d = 0.0f;
#pragma unroll
            for (int j = 0; j < 8; ++j) acc[j] = 0.f;
        }
    }
    int r0 = rowstart[n], r1 = rowstart[n + 1];
    int cnt = r1 - r0;
    if (cnt > 0) {
        // prologue: group 0 loads
        f16x8 uA[4];
        float rA[4];
        {
            int sA[4];
#pragma unroll
            for (int i = 0; i < 4; ++i) sA[i] = csr_src[min(r0 + 2 * i + half, r1 - 1)];
#pragma unroll
            for (int i = 0; i < 4; ++i) {
                uA[i] = *(const f16x8*)&hf[(size_t)sA[i] * FDIM + fo];
                rA[i] = ssrc[sA[i] * HEADS + head];
            }
        }
        for (int base = 0; base < cnt; base += 8) {
            // issue next group's loads before computing the current group
            f16x8 uB[4];
            float rB[4];
            int nb = base + 8;
            if (nb < cnt) {
                int sB[4];
#pragma unroll
                for (int i = 0; i < 4; ++i) sB[i] = csr_src[min(r0 + nb + 2 * i + half, r1 - 1)];
#pragma unroll
                for (int i = 0; i < 4; ++i) {
                    uB[i] = *(const f16x8*)&hf[(size_t)sB[i] * FDIM + fo];
                    rB[i] = ssrc[sB[i] * HEADS + head];
                }
            }
            // compute current group
            float c[4], w[4];
#pragma unroll
            for (int i = 0; i < 4; ++i) {
                float sc = rA[i] + sd;
                sc = (sc > 0.f) ? sc : NEG_SLOPE * sc;
                c[i] = (base + 2 * i + half < cnt) ? sc : -1e30f;
            }
            float mx = fmaxf(fmaxf(c[0], c[1]), fmaxf(c[2], c[3]));
            float mn = fmaxf(m, mx);
            float wa = __builtin_amdgcn_exp2f(m - mn);
#pragma unroll
            for (int i = 0; i < 4; ++i) w[i] = __builtin_amdgcn_exp2f(c[i] - mn);
            h16x2 h01 = __builtin_amdgcn_cvt_pkrtz(w[0], w[1]);
            h16x2 h23 = __builtin_amdgcn_cvt_pkrtz(w[2], w[3]);
#pragma unroll
            for (int j = 0; j < 8; ++j) {
                h16x2 p01 = {(__fp16)uA[0][j], (__fp16)uA[1][j]};
                h16x2 p23 = {(__fp16)uA[2][j], (__fp16)uA[3][j]};
                float tj = acc[j] * wa;
                tj = __builtin_amdgcn_fdot2(h01, p01, tj, false);
                tj = __builtin_amdgcn_fdot2(h23, p23, tj, false);
                acc[j] = tj;
            }
            float w01 = (float)h01[0] + (float)h01[1];
            float w23 = (float)h23[0] + (float)h23[1];
            d = d * wa + (w01 + w23);
            m = mn;
            // rotate pipeline
#pragma unroll
            for (int i = 0; i < 4; ++i) {
                uA[i] = uB[i];
                rA[i] = rB[i];
            }
        }
    }
    // ---- merge the two half-wave flash states ----
    {
        float pm = __shfl_xor(m, 32);
        float mn = fmaxf(m, pm);
        float wa = __builtin_amdgcn_exp2f(m - mn);
        float wb = __builtin_amdgcn_exp2f(pm - mn);
        float pd = __shfl_xor(d, 32);
        d = d * wa + pd * wb;
#pragma unroll
        for (int j = 0; j < 8; ++j) {
            float pa = __shfl_xor(acc[j], 32);
            acc[j] = acc[j] * wa + pa * wb;
        }
    }
    if (half == 0) {
        float inv = 1.0f / d;
        float4 b0 = *(const float4*)&bias[fo];
        float4 b1 = *(const float4*)&bias[fo + 4];
        f16x8 o;
        o[0] = (_Float16)fmaxf(acc[0] * inv + b0.x, 0.f);
        o[1] = (_Float16)fmaxf(acc[1] * inv + b0.y, 0.f);
        o[2] = (_Float16)fmaxf(acc[2] * inv + b0.z, 0.f);
        o[3] = (_Float16)fmaxf(acc[3] * inv + b0.w, 0.f);
        o[4] = (_Float16)fmaxf(acc[4] * inv + b1.x, 0.f);
        o[5] = (_Float16)fmaxf(acc[5] * inv + b1.y, 0.f);
        o[6] = (_Float16)fmaxf(acc[6] * inv + b1.z, 0.f);
        o[7] = (_Float16)fmaxf(acc[7] * inv + b1.w, 0.f);
        *(f16x8*)&outf[(size_t)n * FDIM + fo] = o;
    }
}

// ---------------- pooling (batch sorted, f16 plane) ----------------

__global__ __launch_bounds__(256) void k_pool(const _Float16* __restrict__ hf,
                                              const int* __restrict__ batch,
                                              float* __restrict__ pooled, int N) {
    int f = threadIdx.x;
    int n0 = blockIdx.x * 128;
    if (n0 >= N) return;
    int n1 = min(n0 + 128, N);
    int g = batch[n0];
    float run = 0.f;
    for (int n = n0; n < n1; ++n) {
        int gn = batch[n];
        if (gn != g) {
            atomicAdd(&pooled[g * FDIM + f], run);
            run = 0.f;
            g = gn;
        }
        run += (float)hf[(size_t)n * FDIM + f];
    }
    atomicAdd(&pooled[g * FDIM + f], run);
}

// ---------------- final classifier ----------------

__global__ __launch_bounds__(256) void k_final(const float* __restrict__ pooled,
                                               const float* __restrict__ Wc,
                                               const float* __restrict__ bc,
                                               float* __restrict__ out) {
    int tid = blockIdx.x * 256 + threadIdx.x;
    int g = tid >> 4, o = tid & 15;
    float s = bc[o];
    for (int k = 0; k < FDIM; ++k) s += pooled[g * FDIM + k] * Wc[k * OUTCH + o];
    out[g * OUTCH + o] = s;
}

// ---------------- launch ----------------

extern "C" void kernel_launch(void* const* d_in, const int* in_sizes, int n_in,
                              void* d_out, int out_size, void* d_ws, size_t ws_size,
                              hipStream_t stream) {
    const float* x = (const float*)d_in[0];
    const int* edge_index = (const int*)d_in[2];
    const int* batch = (const int*)d_in[3];
    const float* W[3]    = {(const float*)d_in[4], (const float*)d_in[8],  (const float*)d_in[12]};
    const float* asrc[3] = {(const float*)d_in[5], (const float*)d_in[9],  (const float*)d_in[13]};
    const float* adst[3] = {(const float*)d_in[6], (const float*)d_in[10], (const float*)d_in[14]};
    const float* bias[3] = {(const float*)d_in[7], (const float*)d_in[11], (const float*)d_in[15]};
    const float* Wc = (const float*)d_in[16];
    const float* bc = (const float*)d_in[17];

    const int N = in_sizes[3];
    const int E = in_sizes[2] / 2;
    const int* e_src = edge_index;
    const int* e_dst = edge_index + E;

    char* ws = (char*)d_ws;
    size_t off = 0;
    _Float16* hb = (_Float16*)(ws + off); off += (size_t)N * FDIM * 2;
    _Float16* xf = (_Float16*)(ws + off); off += (size_t)N * INCH * 2;
    _Float16* P  = (_Float16*)(ws + off); off += (size_t)N * FDIM * 2;
    float* ssrc = (float*)(ws + off); off += (size_t)N * HEADS * 4;
    float* sdst = (float*)(ws + off); off += (size_t)N * HEADS * 4;
    int* rowstart = (int*)(ws + off); off += ((size_t)(N + 1) * 4 + 255) / 256 * 256;
    int* counts = (int*)(ws + off); off += (size_t)N * 4;
    int* cursor = (int*)(ws + off); off += (size_t)N * 4;
    int* csr_src = (int*)(ws + off); off += (size_t)E * 4;
    float* pooled = (float*)(ws + off); off += (size_t)NGRAPHS * FDIM * 4;
    int* bsum = (int*)(ws + off); off += ((size_t)((N + 255) / 256) * 4 + 255) / 256 * 256;
    _Float16* Wt[3];
    int Ks[3] = {INCH, FDIM, FDIM};
    for (int l = 0; l < 3; ++l) {
        Wt[l] = (_Float16*)(ws + off); off += (size_t)256 * Ks[l] * 2;
    }

    const int nb = (N + 255) / 256;

    // ---- CSR build ----
    hipMemsetAsync(counts, 0, (size_t)N * 4, stream);
    k_hist<<<(E + 255) / 256, 256, 0, stream>>>(e_dst, E, counts);
    k_blocksum<<<nb, 256, 0, stream>>>(counts, N, bsum);
    k_scanfinal<<<nb, 256, 0, stream>>>(counts, bsum, N, rowstart, cursor);
    k_scatter<<<(E + 255) / 256, 256, 0, stream>>>(e_src, e_dst, E, cursor, csr_src);

    // ---- fused input + weight conversion (1 launch) ----
    {
        int bx = (N * INCH / 4) / 256;
        int btot = bx + (Ks[0] * 256) / 256 + (Ks[1] * 256) / 256 + (Ks[2] * 256) / 256;
        k_convert<<<btot, 256, 0, stream>>>(x, xf, bx, W[0], Wt[0], W[1], Wt[1], W[2], Wt[2]);
    }

    // ---- 3 GAT layers ----
    const _Float16* Af = xf;
    for (int l = 0; l < 3; ++l) {
        int K = Ks[l];
        k_gemm_mfma<<<(N + BM - 1) / BM, 256, 0, stream>>>(Af, Wt[l], asrc[l], adst[l],
                                                           hb, ssrc, sdst, N, K);
        k_aggregate<<<(N + 3) / 4, 256, 0, stream>>>(hb, ssrc, sdst, rowstart, csr_src,
                                                     bias[l], P, N);
        Af = P;
    }

    // ---- pool + classifier ----
    hipMemsetAsync(pooled, 0, (size_t)NGRAPHS * FDIM * 4, stream);
    k_pool<<<(N + 127) / 128, 256, 0, stream>>>(P, batch, pooled, N);
    k_final<<<4, 256, 0, stream>>>(pooled, Wc, bc, (float*)d_out);
}

// Round 17
// 328.975 us; speedup vs baseline: 1.0188x; 1.0088x over previous
//
#include <hip/hip_runtime.h>
#include <hip/hip_bf16.h>

#define NNODES 50000
#define NEDGES 500000
#define INCH 128
#define HID 64
#define HEADS 4
#define FDIM 256
#define NGRAPHS 64
#define OUTCH 16
#define NEG_SLOPE 0.2f
#define LOG2E 1.44269504089f

#define BM 64
#define BN 256
#define BK 32

typedef float f32x4 __attribute__((ext_vector_type(4)));
typedef _Float16 f16x8 __attribute__((ext_vector_type(8)));
typedef _Float16 f16x4 __attribute__((ext_vector_type(4)));

__device__ inline void gld_lds16(const void* g, void* l) {
    __builtin_amdgcn_global_load_lds((__attribute__((address_space(1))) void*)g,
                                     (__attribute__((address_space(3))) void*)l, 16, 0, 0);
}

// ---------------- CSR build ----------------

__global__ void k_hist(const int* __restrict__ dst, int E, int* __restrict__ counts) {
    int i = blockIdx.x * blockDim.x + threadIdx.x;
    if (i < E) atomicAdd(&counts[dst[i]], 1);
}

__global__ __launch_bounds__(256) void k_blocksum(const int* __restrict__ counts, int N,
                                                  int* __restrict__ bsum) {
    int idx = blockIdx.x * 256 + threadIdx.x;
    int v = (idx < N) ? counts[idx] : 0;
#pragma unroll
    for (int off = 32; off; off >>= 1) v += __shfl_xor(v, off);
    __shared__ int wsum[4];
    if ((threadIdx.x & 63) == 0) wsum[threadIdx.x >> 6] = v;
    __syncthreads();
    if (threadIdx.x == 0) bsum[blockIdx.x] = wsum[0] + wsum[1] + wsum[2] + wsum[3];
}

__global__ __launch_bounds__(256) void k_scanfinal(const int* __restrict__ counts,
                                                   const int* __restrict__ bsum, int N,
                                                   int* __restrict__ rowstart,
                                                   int* __restrict__ cursor) {
    __shared__ int tmp[256];
    __shared__ int wsum[4];
    int t = threadIdx.x, b = blockIdx.x;
    int p = 0;
    for (int i = t; i < b; i += 256) p += bsum[i];
#pragma unroll
    for (int off = 32; off; off >>= 1) p += __shfl_xor(p, off);
    int idx = b * 256 + t;
    int v = (idx < N) ? counts[idx] : 0;
    tmp[t] = v;
    if ((t & 63) == 0) wsum[t >> 6] = p;
    __syncthreads();
    int bp = wsum[0] + wsum[1] + wsum[2] + wsum[3];
    for (int off = 1; off < 256; off <<= 1) {
        int u = (t >= off) ? tmp[t - off] : 0;
        __syncthreads();
        tmp[t] += u;
        __syncthreads();
    }
    if (idx < N) {
        int incl = bp + tmp[t];
        rowstart[idx + 1] = incl;
        cursor[idx] = incl - v;
    }
    if (idx == 0) rowstart[0] = 0;
}

__global__ void k_scatter(const int* __restrict__ src, const int* __restrict__ dst, int E,
                          int* __restrict__ cursor, int* __restrict__ csr_src) {
    int i = blockIdx.x * blockDim.x + threadIdx.x;
    if (i < E) {
        int p = atomicAdd(&cursor[dst[i]], 1);
        csr_src[p] = src[i];
    }
}

// ---------------- fused conversion: x -> f16 plane, W[l] -> transposed f16 ----------------

__device__ inline void wdecomp_body(const float* __restrict__ W, _Float16* __restrict__ Wt,
                                    int K, int bb) {
    int i = bb * 256 + threadIdx.x;
    int k = i >> 8, n = i & 255;
    Wt[n * K + k] = (_Float16)W[i];
}

__global__ __launch_bounds__(256) void k_convert(
    const float* __restrict__ X, _Float16* __restrict__ Xf, int bx,
    const float* __restrict__ W0, _Float16* __restrict__ Wt0,
    const float* __restrict__ W1, _Float16* __restrict__ Wt1,
    const float* __restrict__ W2, _Float16* __restrict__ Wt2) {
    int b = blockIdx.x;
    if (b < bx) {
        int i = b * 256 + threadIdx.x;
        float4 v = ((const float4*)X)[i];
        f16x4 o = {(_Float16)v.x, (_Float16)v.y, (_Float16)v.z, (_Float16)v.w};
        ((f16x4*)Xf)[i] = o;
    } else if (b < bx + 128) {
        wdecomp_body(W0, Wt0, INCH, b - bx);
    } else if (b < bx + 384) {
        wdecomp_body(W1, Wt1, FDIM, b - bx - 128);
    } else {
        wdecomp_body(W2, Wt2, FDIM, b - bx - 384);
    }
}

// ---------------- f16 MFMA GEMM, BM=64, double-buffered gld_lds, fused scores ----------------
// Scores pre-scaled by LOG2E (aggregate uses raw v_exp_f32).
// NEW: H stored via LDS bounce -> fully coalesced f16x8 stores (was 64 scalar 2B stores/thread).

__global__ __launch_bounds__(256) void k_gemm_mfma(
    const _Float16* __restrict__ A, const _Float16* __restrict__ B,
    const float* __restrict__ av, const float* __restrict__ dv,
    _Float16* __restrict__ Hf,
    float* __restrict__ ssrcO, float* __restrict__ sdstO, int M, int K) {
    __shared__ _Float16 sA[2][BM * BK];
    __shared__ _Float16 sB[2][BN * BK];   // 32 KB; reused as 64x256 H bounce after K-loop

    const int t = threadIdx.x;
    const int row0 = blockIdx.x * BM;
    const int wv = t >> 6, ln = t & 63, lr = ln & 15, lk = ln >> 4;

    const int ar = wv * 16 + (ln >> 2);
    const int alc = (ln & 3) ^ ((ar >> 1) & 3);
    const size_t agoff = (size_t)min(row0 + ar, M - 1) * K + alc * 8;
    const int fsc = lk ^ ((lr >> 1) & 3);

    f32x4 acc[4][4] = {};
    const int nt = K / BK;

#define STAGE(tt, p)                                                        \
    do {                                                                    \
        int _k0 = (tt)*BK;                                                  \
        gld_lds16(A + agoff + _k0, &sA[p][wv * 512]);                       \
        _Pragma("unroll") for (int _j = 0; _j < 4; ++_j) {                  \
            int _br = _j * 64 + ar;                                         \
            gld_lds16(B + (size_t)_br * K + _k0 + alc * 8,                  \
                      &sB[p][_j * 2048 + wv * 512]);                        \
        }                                                                   \
    } while (0)

    STAGE(0, 0);
    __syncthreads();
    for (int tt = 0; tt < nt; ++tt) {
        int cur = tt & 1;
        if (tt + 1 < nt) STAGE(tt + 1, cur ^ 1);

        f16x8 af[4];
#pragma unroll
        for (int mi = 0; mi < 4; ++mi)
            af[mi] = *(const f16x8*)&sA[cur][(mi * 16 + lr) * BK + fsc * 8];
#pragma unroll
        for (int ni = 0; ni < 4; ++ni) {
            f16x8 bf = *(const f16x8*)&sB[cur][(wv * 64 + ni * 16 + lr) * BK + fsc * 8];
#pragma unroll
            for (int mi = 0; mi < 4; ++mi)
                acc[mi][ni] = __builtin_amdgcn_mfma_f32_16x16x32_f16(af[mi], bf, acc[mi][ni], 0, 0, 0);
        }
        __syncthreads();
    }
#undef STAGE

    // ---- epilogue A: H via LDS bounce. Chunk swizzle cs = c ^ ((row>>2)&7) gives each
    // lk-group a disjoint bank set on write; phase-2 reads are conflict-free.
    _Float16* Hs = &sB[0][0];   // 16384 f16 = 64 x 256
#pragma unroll
    for (int mi = 0; mi < 4; ++mi) {
#pragma unroll
        for (int ni = 0; ni < 4; ++ni) {
            int col = wv * 64 + ni * 16 + lr;
            int c = col >> 3, cl = col & 7;
#pragma unroll
            for (int j = 0; j < 4; ++j) {
                int row = mi * 16 + lk * 4 + j;
                int cs = c ^ ((row >> 2) & 7);
                Hs[row * 256 + (cs << 3) + cl] = (_Float16)acc[mi][ni][j];
            }
        }
    }
    __syncthreads();
#pragma unroll
    for (int i = 0; i < 8; ++i) {
        int f = i * 256 + t;
        int row = f >> 5, ccl = f & 31;
        int cs = ccl ^ ((row >> 2) & 7);
        if (row0 + row < M)
            *(f16x8*)(Hf + (size_t)(row0 + row) * FDIM + ccl * 8) =
                *(const f16x8*)&Hs[row * 256 + (cs << 3)];
    }

    // ---- epilogue B: fused score partials from registers (unchanged) ----
    float ps[4][4] = {}, pd[4][4] = {};
#pragma unroll
    for (int ni = 0; ni < 4; ++ni) {
        int col = wv * 64 + ni * 16 + lr;
        float a_s = av[col] * LOG2E, a_d = dv[col] * LOG2E;
#pragma unroll
        for (int mi = 0; mi < 4; ++mi) {
            f32x4 v = acc[mi][ni];
#pragma unroll
            for (int j = 0; j < 4; ++j) {
                ps[mi][j] += v[j] * a_s;
                pd[mi][j] += v[j] * a_d;
            }
        }
    }
#pragma unroll
    for (int mi = 0; mi < 4; ++mi) {
#pragma unroll
        for (int j = 0; j < 4; ++j) {
            float s = ps[mi][j], q = pd[mi][j];
            s += __shfl_xor(s, 1); s += __shfl_xor(s, 2);
            s += __shfl_xor(s, 4); s += __shfl_xor(s, 8);
            q += __shfl_xor(q, 1); q += __shfl_xor(q, 2);
            q += __shfl_xor(q, 4); q += __shfl_xor(q, 8);
            if (lr == 0) {
                int r = row0 + mi * 16 + lk * 4 + j;
                if (r < M) {
                    ssrcO[r * HEADS + wv] = s;
                    sdstO[r * HEADS + wv] = q;
                }
            }
        }
    }
}

// ---------------- flash softmax + aggregation: split-wave (even/odd edges), f16x8 lanes ----------------
// (R13 measured-best version: plain FMA inner, no pipeline)

__global__ __launch_bounds__(256) void k_aggregate(
    const _Float16* __restrict__ hf,
    const float* __restrict__ ssrc, const float* __restrict__ sdst,
    const int* __restrict__ rowstart, const int* __restrict__ csr_src,
    const float* __restrict__ bias,
    _Float16* __restrict__ outf, int N) {
    int wv = threadIdx.x >> 6, ln = threadIdx.x & 63;
    int n = blockIdx.x * 4 + wv;
    if (n >= N) return;
    int half = ln >> 5;        // 0: even edges (+self), 1: odd edges
    int lh = ln & 31;
    int head = lh >> 3;        // 8 lanes per head
    int fo = lh * 8;           // 8 features per lane
    float sd = sdst[n * HEADS + head];

    float m, d;
    float acc[8];
    {
        f16x8 sv = *(const f16x8*)&hf[(size_t)n * FDIM + fo];
        float e = ssrc[n * HEADS + head] + sd;
        e = (e > 0.f) ? e : NEG_SLOPE * e;
        if (half == 0) {
            m = e; d = 1.0f;
#pragma unroll
            for (int j = 0; j < 8; ++j) acc[j] = (float)sv[j];
        } else {
            m = -1e30f; d = 0.0f;
#pragma unroll
            for (int j = 0; j < 8; ++j) acc[j] = 0.f;
        }
    }
    int r0 = rowstart[n], r1 = rowstart[n + 1];
    int cnt = r1 - r0;
    for (int base = 0; base < cnt; base += 8) {
        int s[4];
        f16x8 u[4];
        float c[4], w[4];
#pragma unroll
        for (int i = 0; i < 4; ++i)
            s[i] = csr_src[min(r0 + base + 2 * i + half, r1 - 1)];
#pragma unroll
        for (int i = 0; i < 4; ++i) u[i] = *(const f16x8*)&hf[(size_t)s[i] * FDIM + fo];
#pragma unroll
        for (int i = 0; i < 4; ++i) {
            float sc = ssrc[s[i] * HEADS + head] + sd;
            sc = (sc > 0.f) ? sc : NEG_SLOPE * sc;
            c[i] = (base + 2 * i + half < cnt) ? sc : -1e30f;
        }
        float mx = fmaxf(fmaxf(c[0], c[1]), fmaxf(c[2], c[3]));
        float mn = fmaxf(m, mx);
        float wa = __builtin_amdgcn_exp2f(m - mn);
#pragma unroll
        for (int i = 0; i < 4; ++i) w[i] = __builtin_amdgcn_exp2f(c[i] - mn);
#pragma unroll
        for (int j = 0; j < 8; ++j) {
            float sj = w[0] * (float)u[0][j] + w[1] * (float)u[1][j] +
                       w[2] * (float)u[2][j] + w[3] * (float)u[3][j];
            acc[j] = acc[j] * wa + sj;
        }
        d = d * wa + ((w[0] + w[1]) + (w[2] + w[3]));
        m = mn;
    }
    // ---- merge the two half-wave flash states ----
    {
        float pm = __shfl_xor(m, 32);
        float mn = fmaxf(m, pm);
        float wa = __builtin_amdgcn_exp2f(m - mn);
        float wb = __builtin_amdgcn_exp2f(pm - mn);
        float pd = __shfl_xor(d, 32);
        d = d * wa + pd * wb;
#pragma unroll
        for (int j = 0; j < 8; ++j) {
            float pa = __shfl_xor(acc[j], 32);
            acc[j] = acc[j] * wa + pa * wb;
        }
    }
    if (half == 0) {
        float inv = 1.0f / d;
        float4 b0 = *(const float4*)&bias[fo];
        float4 b1 = *(const float4*)&bias[fo + 4];
        f16x8 o;
        o[0] = (_Float16)fmaxf(acc[0] * inv + b0.x, 0.f);
        o[1] = (_Float16)fmaxf(acc[1] * inv + b0.y, 0.f);
        o[2] = (_Float16)fmaxf(acc[2] * inv + b0.z, 0.f);
        o[3] = (_Float16)fmaxf(acc[3] * inv + b0.w, 0.f);
        o[4] = (_Float16)fmaxf(acc[4] * inv + b1.x, 0.f);
        o[5] = (_Float16)fmaxf(acc[5] * inv + b1.y, 0.f);
        o[6] = (_Float16)fmaxf(acc[6] * inv + b1.z, 0.f);
        o[7] = (_Float16)fmaxf(acc[7] * inv + b1.w, 0.f);
        *(f16x8*)&outf[(size_t)n * FDIM + fo] = o;
    }
}

// ---------------- pooling (batch sorted, f16 plane) ----------------

__global__ __launch_bounds__(256) void k_pool(const _Float16* __restrict__ hf,
                                              const int* __restrict__ batch,
                                              float* __restrict__ pooled, int N) {
    int f = threadIdx.x;
    int n0 = blockIdx.x * 128;
    if (n0 >= N) return;
    int n1 = min(n0 + 128, N);
    int g = batch[n0];
    float run = 0.f;
    for (int n = n0; n < n1; ++n) {
        int gn = batch[n];
        if (gn != g) {
            atomicAdd(&pooled[g * FDIM + f], run);
            run = 0.f;
            g = gn;
        }
        run += (float)hf[(size_t)n * FDIM + f];
    }
    atomicAdd(&pooled[g * FDIM + f], run);
}

// ---------------- final classifier ----------------

__global__ __launch_bounds__(256) void k_final(const float* __restrict__ pooled,
                                               const float* __restrict__ Wc,
                                               const float* __restrict__ bc,
                                               float* __restrict__ out) {
    int tid = blockIdx.x * 256 + threadIdx.x;
    int g = tid >> 4, o = tid & 15;
    float s = bc[o];
    for (int k = 0; k < FDIM; ++k) s += pooled[g * FDIM + k] * Wc[k * OUTCH + o];
    out[g * OUTCH + o] = s;
}

// ---------------- launch ----------------

extern "C" void kernel_launch(void* const* d_in, const int* in_sizes, int n_in,
                              void* d_out, int out_size, void* d_ws, size_t ws_size,
                              hipStream_t stream) {
    const float* x = (const float*)d_in[0];
    const int* edge_index = (const int*)d_in[2];
    const int* batch = (const int*)d_in[3];
    const float* W[3]    = {(const float*)d_in[4], (const float*)d_in[8],  (const float*)d_in[12]};
    const float* asrc[3] = {(const float*)d_in[5], (const float*)d_in[9],  (const float*)d_in[13]};
    const float* adst[3] = {(const float*)d_in[6], (const float*)d_in[10], (const float*)d_in[14]};
    const float* bias[3] = {(const float*)d_in[7], (const float*)d_in[11], (const float*)d_in[15]};
    const float* Wc = (const float*)d_in[16];
    const float* bc = (const float*)d_in[17];

    const int N = in_sizes[3];
    const int E = in_sizes[2] / 2;
    const int* e_src = edge_index;
    const int* e_dst = edge_index + E;

    char* ws = (char*)d_ws;
    size_t off = 0;
    _Float16* hb = (_Float16*)(ws + off); off += (size_t)N * FDIM * 2;
    _Float16* xf = (_Float16*)(ws + off); off += (size_t)N * INCH * 2;
    _Float16* P  = (_Float16*)(ws + off); off += (size_t)N * FDIM * 2;
    float* ssrc = (float*)(ws + off); off += (size_t)N * HEADS * 4;
    float* sdst = (float*)(ws + off); off += (size_t)N * HEADS * 4;
    int* rowstart = (int*)(ws + off); off += ((size_t)(N + 1) * 4 + 255) / 256 * 256;
    int* counts = (int*)(ws + off); off += (size_t)N * 4;
    int* cursor = (int*)(ws + off); off += (size_t)N * 4;
    int* csr_src = (int*)(ws + off); off += (size_t)E * 4;
    float* pooled = (float*)(ws + off); off += (size_t)NGRAPHS * FDIM * 4;
    int* bsum = (int*)(ws + off); off += ((size_t)((N + 255) / 256) * 4 + 255) / 256 * 256;
    _Float16* Wt[3];
    int Ks[3] = {INCH, FDIM, FDIM};
    for (int l = 0; l < 3; ++l) {
        Wt[l] = (_Float16*)(ws + off); off += (size_t)256 * Ks[l] * 2;
    }

    const int nb = (N + 255) / 256;

    // ---- CSR build ----
    hipMemsetAsync(counts, 0, (size_t)N * 4, stream);
    k_hist<<<(E + 255) / 256, 256, 0, stream>>>(e_dst, E, counts);
    k_blocksum<<<nb, 256, 0, stream>>>(counts, N, bsum);
    k_scanfinal<<<nb, 256, 0, stream>>>(counts, bsum, N, rowstart, cursor);
    k_scatter<<<(E + 255) / 256, 256, 0, stream>>>(e_src, e_dst, E, cursor, csr_src);

    // ---- fused input + weight conversion (1 launch) ----
    {
        int bx = (N * INCH / 4) / 256;
        int btot = bx + (Ks[0] * 256) / 256 + (Ks[1] * 256) / 256 + (Ks[2] * 256) / 256;
        k_convert<<<btot, 256, 0, stream>>>(x, xf, bx, W[0], Wt[0], W[1], Wt[1], W[2], Wt[2]);
    }

    // ---- 3 GAT layers ----
    const _Float16* Af = xf;
    for (int l = 0; l < 3; ++l) {
        int K = Ks[l];
        k_gemm_mfma<<<(N + BM - 1) / BM, 256, 0, stream>>>(Af, Wt[l], asrc[l], adst[l],
                                                           hb, ssrc, sdst, N, K);
        k_aggregate<<<(N + 3) / 4, 256, 0, stream>>>(hb, ssrc, sdst, rowstart, csr_src,
                                                     bias[l], P, N);
        Af = P;
    }

    // ---- pool + classifier ----
    hipMemsetAsync(pooled, 0, (size_t)NGRAPHS * FDIM * 4, stream);
    k_pool<<<(N + 127) / 128, 256, 0, stream>>>(P, batch, pooled, N);
    k_final<<<4, 256, 0, stream>>>(pooled, Wc, bc, (float*)d_out);
}

// Round 18
// 320.233 us; speedup vs baseline: 1.0466x; 1.0273x over previous
//
#include <hip/hip_runtime.h>
#include <hip/hip_bf16.h>

#define NNODES 50000
#define NEDGES 500000
#define INCH 128
#define HID 64
#define HEADS 4
#define FDIM 256
#define NGRAPHS 64
#define OUTCH 16
#define NEG_SLOPE 0.2f
#define LOG2E 1.44269504089f

#define BM 64
#define BN 256
#define BK 32

typedef float f32x4 __attribute__((ext_vector_type(4)));
typedef _Float16 f16x8 __attribute__((ext_vector_type(8)));
typedef _Float16 f16x4 __attribute__((ext_vector_type(4)));

__device__ inline void gld_lds16(const void* g, void* l) {
    __builtin_amdgcn_global_load_lds((__attribute__((address_space(1))) void*)g,
                                     (__attribute__((address_space(3))) void*)l, 16, 0, 0);
}

// ---------------- CSR build ----------------

__global__ void k_hist(const int* __restrict__ dst, int E, int* __restrict__ counts) {
    int i = blockIdx.x * blockDim.x + threadIdx.x;
    if (i < E) atomicAdd(&counts[dst[i]], 1);
}

__global__ __launch_bounds__(256) void k_blocksum(const int* __restrict__ counts, int N,
                                                  int* __restrict__ bsum) {
    int idx = blockIdx.x * 256 + threadIdx.x;
    int v = (idx < N) ? counts[idx] : 0;
#pragma unroll
    for (int off = 32; off; off >>= 1) v += __shfl_xor(v, off);
    __shared__ int wsum[4];
    if ((threadIdx.x & 63) == 0) wsum[threadIdx.x >> 6] = v;
    __syncthreads();
    if (threadIdx.x == 0) bsum[blockIdx.x] = wsum[0] + wsum[1] + wsum[2] + wsum[3];
}

__global__ __launch_bounds__(256) void k_scanfinal(const int* __restrict__ counts,
                                                   const int* __restrict__ bsum, int N,
                                                   int* __restrict__ rowstart,
                                                   int* __restrict__ cursor) {
    __shared__ int tmp[256];
    __shared__ int wsum[4];
    int t = threadIdx.x, b = blockIdx.x;
    int p = 0;
    for (int i = t; i < b; i += 256) p += bsum[i];
#pragma unroll
    for (int off = 32; off; off >>= 1) p += __shfl_xor(p, off);
    int idx = b * 256 + t;
    int v = (idx < N) ? counts[idx] : 0;
    tmp[t] = v;
    if ((t & 63) == 0) wsum[t >> 6] = p;
    __syncthreads();
    int bp = wsum[0] + wsum[1] + wsum[2] + wsum[3];
    for (int off = 1; off < 256; off <<= 1) {
        int u = (t >= off) ? tmp[t - off] : 0;
        __syncthreads();
        tmp[t] += u;
        __syncthreads();
    }
    if (idx < N) {
        int incl = bp + tmp[t];
        rowstart[idx + 1] = incl;
        cursor[idx] = incl - v;
    }
    if (idx == 0) rowstart[0] = 0;
}

__global__ void k_scatter(const int* __restrict__ src, const int* __restrict__ dst, int E,
                          int* __restrict__ cursor, int* __restrict__ csr_src) {
    int i = blockIdx.x * blockDim.x + threadIdx.x;
    if (i < E) {
        int p = atomicAdd(&cursor[dst[i]], 1);
        csr_src[p] = src[i];
    }
}

// ---------------- fused conversion: x -> f16 plane, W[l] -> transposed f16 ----------------

__device__ inline void wdecomp_body(const float* __restrict__ W, _Float16* __restrict__ Wt,
                                    int K, int bb) {
    int i = bb * 256 + threadIdx.x;
    int k = i >> 8, n = i & 255;
    Wt[n * K + k] = (_Float16)W[i];
}

__global__ __launch_bounds__(256) void k_convert(
    const float* __restrict__ X, _Float16* __restrict__ Xf, int bx,
    const float* __restrict__ W0, _Float16* __restrict__ Wt0,
    const float* __restrict__ W1, _Float16* __restrict__ Wt1,
    const float* __restrict__ W2, _Float16* __restrict__ Wt2) {
    int b = blockIdx.x;
    if (b < bx) {
        int i = b * 256 + threadIdx.x;
        float4 v = ((const float4*)X)[i];
        f16x4 o = {(_Float16)v.x, (_Float16)v.y, (_Float16)v.z, (_Float16)v.w};
        ((f16x4*)Xf)[i] = o;
    } else if (b < bx + 128) {
        wdecomp_body(W0, Wt0, INCH, b - bx);
    } else if (b < bx + 384) {
        wdecomp_body(W1, Wt1, FDIM, b - bx - 128);
    } else {
        wdecomp_body(W2, Wt2, FDIM, b - bx - 384);
    }
}

// ---------------- f16 MFMA GEMM: 8 waves (512 thr), 100% occupancy target ----------------
// Same 64x256x32 tile + double-buffered gld_lds staging (threads <256, layout unchanged).
// Wave w: rows rh*32..+31 (rh=w>>2), cols colw*64..+63 (colw=w&3); acc[2][4] (~40 VGPR).
// Scores pre-scaled by LOG2E; H stored via swizzled LDS bounce (coalesced f16x8 stores).

__global__ __launch_bounds__(512) void k_gemm_mfma(
    const _Float16* __restrict__ A, const _Float16* __restrict__ B,
    const float* __restrict__ av, const float* __restrict__ dv,
    _Float16* __restrict__ Hf,
    float* __restrict__ ssrcO, float* __restrict__ sdstO, int M, int K) {
    __shared__ _Float16 sA[2][BM * BK];
    __shared__ _Float16 sB[2][BN * BK];   // 32 KB; reused as 64x256 H bounce after K-loop

    const int t = threadIdx.x;
    const int row0 = blockIdx.x * BM;
    const int w = t >> 6, ln = t & 63, lr = ln & 15, lk = ln >> 4;
    const int colw = w & 3, rh = w >> 2;

    // staging mapping (valid for t<256; sv==w there, matching the 4-wave layout)
    const int sv = w & 3;
    const int ar = sv * 16 + (ln >> 2);
    const int alc = (ln & 3) ^ ((ar >> 1) & 3);
    const size_t agoff = (size_t)min(row0 + ar, M - 1) * K + alc * 8;
    const int fsc = lk ^ ((lr >> 1) & 3);

    f32x4 acc[2][4] = {};
    const int nt = K / BK;

#define STAGE(tt, p)                                                        \
    do {                                                                    \
        int _k0 = (tt)*BK;                                                  \
        gld_lds16(A + agoff + _k0, &sA[p][sv * 512]);                       \
        _Pragma("unroll") for (int _j = 0; _j < 4; ++_j) {                  \
            int _br = _j * 64 + ar;                                         \
            gld_lds16(B + (size_t)_br * K + _k0 + alc * 8,                  \
                      &sB[p][_j * 2048 + sv * 512]);                        \
        }                                                                   \
    } while (0)

    if (t < 256) STAGE(0, 0);
    __syncthreads();
    for (int tt = 0; tt < nt; ++tt) {
        int cur = tt & 1;
        if (t < 256 && tt + 1 < nt) STAGE(tt + 1, cur ^ 1);

        f16x8 af[2];
#pragma unroll
        for (int mi = 0; mi < 2; ++mi)
            af[mi] = *(const f16x8*)&sA[cur][(rh * 32 + mi * 16 + lr) * BK + fsc * 8];
#pragma unroll
        for (int ni = 0; ni < 4; ++ni) {
            f16x8 bf = *(const f16x8*)&sB[cur][(colw * 64 + ni * 16 + lr) * BK + fsc * 8];
#pragma unroll
            for (int mi = 0; mi < 2; ++mi)
                acc[mi][ni] = __builtin_amdgcn_mfma_f32_16x16x32_f16(af[mi], bf, acc[mi][ni], 0, 0, 0);
        }
        __syncthreads();
    }
#undef STAGE

    // ---- epilogue A: H via swizzled LDS bounce -> coalesced f16x8 stores ----
    _Float16* Hs = &sB[0][0];   // 16384 f16 = 64 x 256 (spans both sB buffers)
#pragma unroll
    for (int mi = 0; mi < 2; ++mi) {
#pragma unroll
        for (int ni = 0; ni < 4; ++ni) {
            int col = colw * 64 + ni * 16 + lr;
            int c = col >> 3, cl = col & 7;
#pragma unroll
            for (int j = 0; j < 4; ++j) {
                int row = rh * 32 + mi * 16 + lk * 4 + j;
                int cs = c ^ ((row >> 2) & 7);
                Hs[row * 256 + (cs << 3) + cl] = (_Float16)acc[mi][ni][j];
            }
        }
    }
    __syncthreads();
#pragma unroll
    for (int i = 0; i < 4; ++i) {
        int f = i * 512 + t;
        int row = f >> 5, ccl = f & 31;
        int cs = ccl ^ ((row >> 2) & 7);
        if (row0 + row < M)
            *(f16x8*)(Hf + (size_t)(row0 + row) * FDIM + ccl * 8) =
                *(const f16x8*)&Hs[row * 256 + (cs << 3)];
    }

    // ---- epilogue B: fused score partials from registers ----
    float ps[2][4] = {}, pd[2][4] = {};
#pragma unroll
    for (int ni = 0; ni < 4; ++ni) {
        int col = colw * 64 + ni * 16 + lr;
        float a_s = av[col] * LOG2E, a_d = dv[col] * LOG2E;
#pragma unroll
        for (int mi = 0; mi < 2; ++mi) {
            f32x4 v = acc[mi][ni];
#pragma unroll
            for (int j = 0; j < 4; ++j) {
                ps[mi][j] += v[j] * a_s;
                pd[mi][j] += v[j] * a_d;
            }
        }
    }
#pragma unroll
    for (int mi = 0; mi < 2; ++mi) {
#pragma unroll
        for (int j = 0; j < 4; ++j) {
            float s = ps[mi][j], q = pd[mi][j];
            s += __shfl_xor(s, 1); s += __shfl_xor(s, 2);
            s += __shfl_xor(s, 4); s += __shfl_xor(s, 8);
            q += __shfl_xor(q, 1); q += __shfl_xor(q, 2);
            q += __shfl_xor(q, 4); q += __shfl_xor(q, 8);
            if (lr == 0) {
                int r = row0 + rh * 32 + mi * 16 + lk * 4 + j;
                if (r < M) {
                    ssrcO[r * HEADS + colw] = s;
                    sdstO[r * HEADS + colw] = q;
                }
            }
        }
    }
}

// ---------------- flash softmax + aggregation: split-wave (even/odd edges), f16x8 lanes ----------------
// (R13/R17 measured-best version, unchanged)

__global__ __launch_bounds__(256) void k_aggregate(
    const _Float16* __restrict__ hf,
    const float* __restrict__ ssrc, const float* __restrict__ sdst,
    const int* __restrict__ rowstart, const int* __restrict__ csr_src,
    const float* __restrict__ bias,
    _Float16* __restrict__ outf, int N) {
    int wv = threadIdx.x >> 6, ln = threadIdx.x & 63;
    int n = blockIdx.x * 4 + wv;
    if (n >= N) return;
    int half = ln >> 5;
    int lh = ln & 31;
    int head = lh >> 3;
    int fo = lh * 8;
    float sd = sdst[n * HEADS + head];

    float m, d;
    float acc[8];
    {
        f16x8 sv = *(const f16x8*)&hf[(size_t)n * FDIM + fo];
        float e = ssrc[n * HEADS + head] + sd;
        e = (e > 0.f) ? e : NEG_SLOPE * e;
        if (half == 0) {
            m = e; d = 1.0f;
#pragma unroll
            for (int j = 0; j < 8; ++j) acc[j] = (float)sv[j];
        } else {
            m = -1e30f; d = 0.0f;
#pragma unroll
            for (int j = 0; j < 8; ++j) acc[j] = 0.f;
        }
    }
    int r0 = rowstart[n], r1 = rowstart[n + 1];
    int cnt = r1 - r0;
    for (int base = 0; base < cnt; base += 8) {
        int s[4];
        f16x8 u[4];
        float c[4], w[4];
#pragma unroll
        for (int i = 0; i < 4; ++i)
            s[i] = csr_src[min(r0 + base + 2 * i + half, r1 - 1)];
#pragma unroll
        for (int i = 0; i < 4; ++i) u[i] = *(const f16x8*)&hf[(size_t)s[i] * FDIM + fo];
#pragma unroll
        for (int i = 0; i < 4; ++i) {
            float sc = ssrc[s[i] * HEADS + head] + sd;
            sc = (sc > 0.f) ? sc : NEG_SLOPE * sc;
            c[i] = (base + 2 * i + half < cnt) ? sc : -1e30f;
        }
        float mx = fmaxf(fmaxf(c[0], c[1]), fmaxf(c[2], c[3]));
        float mn = fmaxf(m, mx);
        float wa = __builtin_amdgcn_exp2f(m - mn);
#pragma unroll
        for (int i = 0; i < 4; ++i) w[i] = __builtin_amdgcn_exp2f(c[i] - mn);
#pragma unroll
        for (int j = 0; j < 8; ++j) {
            float sj = w[0] * (float)u[0][j] + w[1] * (float)u[1][j] +
                       w[2] * (float)u[2][j] + w[3] * (float)u[3][j];
            acc[j] = acc[j] * wa + sj;
        }
        d = d * wa + ((w[0] + w[1]) + (w[2] + w[3]));
        m = mn;
    }
    // ---- merge the two half-wave flash states ----
    {
        float pm = __shfl_xor(m, 32);
        float mn = fmaxf(m, pm);
        float wa = __builtin_amdgcn_exp2f(m - mn);
        float wb = __builtin_amdgcn_exp2f(pm - mn);
        float pd = __shfl_xor(d, 32);
        d = d * wa + pd * wb;
#pragma unroll
        for (int j = 0; j < 8; ++j) {
            float pa = __shfl_xor(acc[j], 32);
            acc[j] = acc[j] * wa + pa * wb;
        }
    }
    if (half == 0) {
        float inv = 1.0f / d;
        float4 b0 = *(const float4*)&bias[fo];
        float4 b1 = *(const float4*)&bias[fo + 4];
        f16x8 o;
        o[0] = (_Float16)fmaxf(acc[0] * inv + b0.x, 0.f);
        o[1] = (_Float16)fmaxf(acc[1] * inv + b0.y, 0.f);
        o[2] = (_Float16)fmaxf(acc[2] * inv + b0.z, 0.f);
        o[3] = (_Float16)fmaxf(acc[3] * inv + b0.w, 0.f);
        o[4] = (_Float16)fmaxf(acc[4] * inv + b1.x, 0.f);
        o[5] = (_Float16)fmaxf(acc[5] * inv + b1.y, 0.f);
        o[6] = (_Float16)fmaxf(acc[6] * inv + b1.z, 0.f);
        o[7] = (_Float16)fmaxf(acc[7] * inv + b1.w, 0.f);
        *(f16x8*)&outf[(size_t)n * FDIM + fo] = o;
    }
}

// ---------------- pooling (batch sorted, f16 plane) ----------------

__global__ __launch_bounds__(256) void k_pool(const _Float16* __restrict__ hf,
                                              const int* __restrict__ batch,
                                              float* __restrict__ pooled, int N) {
    int f = threadIdx.x;
    int n0 = blockIdx.x * 128;
    if (n0 >= N) return;
    int n1 = min(n0 + 128, N);
    int g = batch[n0];
    float run = 0.f;
    for (int n = n0; n < n1; ++n) {
        int gn = batch[n];
        if (gn != g) {
            atomicAdd(&pooled[g * FDIM + f], run);
            run = 0.f;
            g = gn;
        }
        run += (float)hf[(size_t)n * FDIM + f];
    }
    atomicAdd(&pooled[g * FDIM + f], run);
}

// ---------------- final classifier ----------------

__global__ __launch_bounds__(256) void k_final(const float* __restrict__ pooled,
                                               const float* __restrict__ Wc,
                                               const float* __restrict__ bc,
                                               float* __restrict__ out) {
    int tid = blockIdx.x * 256 + threadIdx.x;
    int g = tid >> 4, o = tid & 15;
    float s = bc[o];
    for (int k = 0; k < FDIM; ++k) s += pooled[g * FDIM + k] * Wc[k * OUTCH + o];
    out[g * OUTCH + o] = s;
}

// ---------------- launch ----------------

extern "C" void kernel_launch(void* const* d_in, const int* in_sizes, int n_in,
                              void* d_out, int out_size, void* d_ws, size_t ws_size,
                              hipStream_t stream) {
    const float* x = (const float*)d_in[0];
    const int* edge_index = (const int*)d_in[2];
    const int* batch = (const int*)d_in[3];
    const float* W[3]    = {(const float*)d_in[4], (const float*)d_in[8],  (const float*)d_in[12]};
    const float* asrc[3] = {(const float*)d_in[5], (const float*)d_in[9],  (const float*)d_in[13]};
    const float* adst[3] = {(const float*)d_in[6], (const float*)d_in[10], (const float*)d_in[14]};
    const float* bias[3] = {(const float*)d_in[7], (const float*)d_in[11], (const float*)d_in[15]};
    const float* Wc = (const float*)d_in[16];
    const float* bc = (const float*)d_in[17];

    const int N = in_sizes[3];
    const int E = in_sizes[2] / 2;
    const int* e_src = edge_index;
    const int* e_dst = edge_index + E;

    char* ws = (char*)d_ws;
    size_t off = 0;
    _Float16* hb = (_Float16*)(ws + off); off += (size_t)N * FDIM * 2;
    _Float16* xf = (_Float16*)(ws + off); off += (size_t)N * INCH * 2;
    _Float16* P  = (_Float16*)(ws + off); off += (size_t)N * FDIM * 2;
    float* ssrc = (float*)(ws + off); off += (size_t)N * HEADS * 4;
    float* sdst = (float*)(ws + off); off += (size_t)N * HEADS * 4;
    int* rowstart = (int*)(ws + off); off += ((size_t)(N + 1) * 4 + 255) / 256 * 256;
    int* counts = (int*)(ws + off); off += (size_t)N * 4;
    int* cursor = (int*)(ws + off); off += (size_t)N * 4;
    int* csr_src = (int*)(ws + off); off += (size_t)E * 4;
    float* pooled = (float*)(ws + off); off += (size_t)NGRAPHS * FDIM * 4;
    int* bsum = (int*)(ws + off); off += ((size_t)((N + 255) / 256) * 4 + 255) / 256 * 256;
    _Float16* Wt[3];
    int Ks[3] = {INCH, FDIM, FDIM};
    for (int l = 0; l < 3; ++l) {
        Wt[l] = (_Float16*)(ws + off); off += (size_t)256 * Ks[l] * 2;
    }

    const int nb = (N + 255) / 256;

    // ---- CSR build ----
    hipMemsetAsync(counts, 0, (size_t)N * 4, stream);
    k_hist<<<(E + 255) / 256, 256, 0, stream>>>(e_dst, E, counts);
    k_blocksum<<<nb, 256, 0, stream>>>(counts, N, bsum);
    k_scanfinal<<<nb, 256, 0, stream>>>(counts, bsum, N, rowstart, cursor);
    k_scatter<<<(E + 255) / 256, 256, 0, stream>>>(e_src, e_dst, E, cursor, csr_src);

    // ---- fused input + weight conversion (1 launch) ----
    {
        int bx = (N * INCH / 4) / 256;
        int btot = bx + (Ks[0] * 256) / 256 + (Ks[1] * 256) / 256 + (Ks[2] * 256) / 256;
        k_convert<<<btot, 256, 0, stream>>>(x, xf, bx, W[0], Wt[0], W[1], Wt[1], W[2], Wt[2]);
    }

    // ---- 3 GAT layers ----
    const _Float16* Af = xf;
    for (int l = 0; l < 3; ++l) {
        int K = Ks[l];
        k_gemm_mfma<<<(N + BM - 1) / BM, 512, 0, stream>>>(Af, Wt[l], asrc[l], adst[l],
                                                           hb, ssrc, sdst, N, K);
        k_aggregate<<<(N + 3) / 4, 256, 0, stream>>>(hb, ssrc, sdst, rowstart, csr_src,
                                                     bias[l], P, N);
        Af = P;
    }

    // ---- pool + classifier ----
    hipMemsetAsync(pooled, 0, (size_t)NGRAPHS * FDIM * 4, stream);
    k_pool<<<(N + 127) / 128, 256, 0, stream>>>(P, batch, pooled, N);
    k_final<<<4, 256, 0, stream>>>(pooled, Wc, bc, (float*)d_out);
}